// Round 17
// baseline (165.076 us; speedup 1.0000x reference)
//
#include <hip/hip_runtime.h>
#include <math.h>

// TokenChoiceTopKRouter, round 17: NO LDS in the main loop.
//
// R10-R16 invariant: period ~ staged_bytes / (~16 B/cycle/CU) regardless of
// barriers, depth, TLP, swizzle -> the global_load_lds LDS-write port is the
// cap (~6x below the vector-load return path). Fix: nothing needs LDS --
// A-fragments are 32 contiguous bytes of one x row per lane (direct
// global->VGPR, 16 lanes/row coalesced); B-fragments are consumed lane-major
// exactly as packed (direct dwordx4 from the L2-resident 1 MB stream).
// Pure register pipeline: 4 named slots, depth-3, all static indices
// (rule #20); compiler's per-register vmcnt counting does the rest.
// Proven numerics (bf16 hi/lo 3-pass MFMA, absmax 50), proven epilogue +
// wsH/k5 histogram (no global atomics).

constexpr int DIM = 4096;
constexpr int NE  = 64;
constexpr int NCH = 128;                         // 32k steps
constexpr size_t WSB_BYTES = 1048576;            // packed B stream (1 MB)

typedef __attribute__((ext_vector_type(8))) short bf16x8;
typedef __attribute__((ext_vector_type(4))) float f32x4;

// ---------- k1: pack w into hi/lo B-fragment stream (R6/R10-proven) ---------
// 16B-unit u = sl*512 + f*64 + lane (sl = 32k step 0..127, f = et*2 + hl).
// Content: e = et*16 + (lane&15), k = sl*32 + 8*(lane>>4) (+j), hi/lo bf16.
__global__ void pack_w(const float* __restrict__ w, ushort* __restrict__ wsB) {
  const int u  = blockIdx.x * 256 + threadIdx.x;   // 65536 units
  const int l  = u & 63;
  const int f  = (u >> 6) & 7;
  const int sl = u >> 9;                           // 0..127
  const int et = f >> 1, hl = f & 1;
  const int e  = et * 16 + (l & 15);
  const int k  = sl * 32 + 8 * (l >> 4);
  const float* src = w + (size_t)e * DIM + k;
  ushort v[8];
#pragma unroll
  for (int j = 0; j < 8; ++j) {
    float xv = src[j];
    unsigned xb = __float_as_uint(xv);
    unsigned hb = xb & 0xffff0000u;                // exact hi (truncation)
    if (hl == 0) {
      v[j] = (ushort)(hb >> 16);
    } else {
      float lf = xv - __uint_as_float(hb);
      unsigned lb = __float_as_uint(lf);
      lb = lb + 0x7fffu + ((lb >> 16) & 1u);       // RNE to bf16
      v[j] = (ushort)(lb >> 16);
    }
  }
  ushort* d = wsB + (size_t)u * 8;
#pragma unroll
  for (int j = 0; j < 8; ++j) d[j] = v[j];
}

// ---------- shared helper: two float4 -> hi/lo bf16x8 ----------
__device__ __forceinline__ void split8(const float4& a0, const float4& a1,
                                       bf16x8& ahi, bf16x8& alo) {
  float av[8] = {a0.x, a0.y, a0.z, a0.w, a1.x, a1.y, a1.z, a1.w};
#pragma unroll
  for (int j = 0; j < 8; ++j) {
    unsigned xb = __float_as_uint(av[j]);
    unsigned hb = xb & 0xffff0000u;
    float lf = av[j] - __uint_as_float(hb);
    unsigned lb = __float_as_uint(lf);
    lb = lb + 0x7fffu + ((lb >> 16) & 1u);
    ahi[j] = (short)(hb >> 16);
    alo[j] = (short)(lb >> 16);
  }
}

// ---------- fused main kernel: register-only pipeline ----------
// 512 blocks x 256 thr (4 waves = 2 token-tiles x 2 expert-halves), 2 blk/CU.
// Wave: 16 tok x 32 exp x full K. Per step: lane loads its A-frag (32 B of
// one x row) + 4 B-frags (lane-major dwordx4) directly to VGPRs; split to
// hi/lo bf16; 6 MFMA. 4 register slots, depth-3 prefetch, no LDS/barriers.
__global__ __launch_bounds__(256, 2)
void router_fused(const float* __restrict__ x, const char* __restrict__ wsB,
                  const float* __restrict__ bias,
                  float* __restrict__ out_scores, float* __restrict__ out_idx,
                  float* __restrict__ wsH) {
  __shared__ float logits[32 * 64];
  __shared__ float hist[NE];
  const int tid  = threadIdx.x;
  const int wv   = tid >> 6;
  const int lane = tid & 63;
  const int tt   = wv & 1;            // token tile 0..1
  const int eh   = wv >> 1;           // expert half 0..1
  const int col  = lane & 15;
  const int kq   = lane >> 4;
  const int tok0 = blockIdx.x * 32;

  // A source: lane's row, k = c*32 + kq*8 .. +8
  const float* xp = x + (size_t)(tok0 + tt * 16 + col) * DIM + kq * 8;
  // B source: frag i of this eh-half at step s: bpe[s*512 + i*64]
  const bf16x8* bpe = (const bf16x8*)wsB + (size_t)(eh * 4) * 64 + lane;

  f32x4 acc[2];
  acc[0] = (f32x4){0.f, 0.f, 0.f, 0.f};
  acc[1] = (f32x4){0.f, 0.f, 0.f, 0.f};

#define LOADS(s, XA, XB, B0, B1, B2, B3)                                     \
  do {                                                                      \
    XA = *(const float4*)(xp + (size_t)(s) * 32);                           \
    XB = *(const float4*)(xp + (size_t)(s) * 32 + 4);                       \
    B0 = bpe[(size_t)(s) * 512 + 0];                                        \
    B1 = bpe[(size_t)(s) * 512 + 64];                                       \
    B2 = bpe[(size_t)(s) * 512 + 128];                                      \
    B3 = bpe[(size_t)(s) * 512 + 192];                                      \
  } while (0)

  // B0/B1 = hi/lo of expert-tile et2=0; B2/B3 = hi/lo of et2=1.
#define COMPUTE(XA, XB, B0, B1, B2, B3)                                      \
  do {                                                                      \
    bf16x8 ahi, alo;                                                        \
    float4 xa_ = XA, xb_ = XB;                                              \
    split8(xa_, xb_, ahi, alo);                                             \
    acc[0] = __builtin_amdgcn_mfma_f32_16x16x32_bf16(ahi, B0, acc[0], 0, 0, 0); \
    acc[0] = __builtin_amdgcn_mfma_f32_16x16x32_bf16(alo, B0, acc[0], 0, 0, 0); \
    acc[0] = __builtin_amdgcn_mfma_f32_16x16x32_bf16(ahi, B1, acc[0], 0, 0, 0); \
    acc[1] = __builtin_amdgcn_mfma_f32_16x16x32_bf16(ahi, B2, acc[1], 0, 0, 0); \
    acc[1] = __builtin_amdgcn_mfma_f32_16x16x32_bf16(alo, B2, acc[1], 0, 0, 0); \
    acc[1] = __builtin_amdgcn_mfma_f32_16x16x32_bf16(ahi, B3, acc[1], 0, 0, 0); \
  } while (0)

  // 4 named register slots; depth-3 software pipeline, all static indices.
  float4 xa0, xb0, xa1, xb1, xa2, xb2, xa3, xb3;
  bf16x8 b00, b01, b02, b03, b10, b11, b12, b13;
  bf16x8 b20, b21, b22, b23, b30, b31, b32, b33;

  LOADS(0, xa0, xb0, b00, b01, b02, b03);
  LOADS(1, xa1, xb1, b10, b11, b12, b13);
  LOADS(2, xa2, xb2, b20, b21, b22, b23);

#pragma unroll 1
  for (int c = 0; c < NCH; c += 4) {
    COMPUTE(xa0, xb0, b00, b01, b02, b03);
    if (c + 3 < NCH) LOADS(c + 3, xa3, xb3, b30, b31, b32, b33);
    COMPUTE(xa1, xb1, b10, b11, b12, b13);
    if (c + 4 < NCH) LOADS(c + 4, xa0, xb0, b00, b01, b02, b03);
    COMPUTE(xa2, xb2, b20, b21, b22, b23);
    if (c + 5 < NCH) LOADS(c + 5, xa1, xb1, b10, b11, b12, b13);
    COMPUTE(xa3, xb3, b30, b31, b32, b33);
    if (c + 6 < NCH) LOADS(c + 6, xa2, xb2, b20, b21, b22, b23);
  }
#undef LOADS
#undef COMPUTE

  // ---- epilogue: full-K logits, 16 tok x 32 exp per wave ----
  if (tid < 64) hist[tid] = 0.f;
  // D layout (m89/R6-verified): e-col = et*16+col, token-row = 4*kq+r
#pragma unroll
  for (int et2 = 0; et2 < 2; ++et2)
#pragma unroll
    for (int rr = 0; rr < 4; ++rr) {
      int t = tt * 16 + 4 * kq + rr;
      int e = eh * 32 + et2 * 16 + col;
      logits[t * 64 + ((e + t) & 63)] = acc[et2][rr];
    }
  __syncthreads();

  // ---- sigmoid + biased top-8 + normalize + LDS hist (proven tail) ----
  if (tid < 32) {
    const int t = tid, gt = tok0 + t;
    float key[8], sv[8];
    int   idx[8];
#pragma unroll
    for (int j = 0; j < 8; ++j) { key[j] = -1e30f; sv[j] = 0.f; idx[j] = 0; }

    for (int e = 0; e < NE; ++e) {
      float l = logits[t * 64 + ((e + t) & 63)];
      float s = 1.0f / (1.0f + expf(-l));
      float k = s + bias[e];
      // bubble-insert; strict > keeps lower index on ties (lax.top_k order)
      float ck = k, cv = s; int ci = e;
#pragma unroll
      for (int j = 0; j < 8; ++j) {
        bool g = ck > key[j];
        float tk = key[j], tv = sv[j]; int ti = idx[j];
        key[j] = g ? ck : tk; sv[j] = g ? cv : tv; idx[j] = g ? ci : ti;
        ck = g ? tk : ck;     cv = g ? tv : cv;    ci = g ? ti : ci;
      }
    }

    float sum = 1e-20f;
#pragma unroll
    for (int j = 0; j < 8; ++j) sum += sv[j];
    float inv = 1.0f / sum;
#pragma unroll
    for (int j = 0; j < 8; ++j) {
      out_scores[gt * 8 + j] = sv[j] * inv;
      out_idx[gt * 8 + j]    = (float)idx[j];
      atomicAdd(&hist[idx[j]], 1.0f);      // LDS atomic
    }
  }
  __syncthreads();
  if (tid < 64) wsH[(size_t)blockIdx.x * NE + tid] = hist[tid];
}

// ---------- k5: reduce per-block histograms -> counts (no atomics) ----------
__global__ __launch_bounds__(256)
void router_k5(const float* __restrict__ wsH, float* __restrict__ counts,
               int nblk) {
  __shared__ float part[256];
  const int e = threadIdx.x & 63, p = threadIdx.x >> 6;
  float s = 0.f;
  for (int b = p; b < nblk; b += 4) s += wsH[(size_t)b * NE + e];
  part[p * 64 + e] = s;
  __syncthreads();
  if (threadIdx.x < 64)
    counts[e] = part[e] + part[64 + e] + part[128 + e] + part[192 + e];
}

// ---------- R6 proven mid-fallback (ws >= 1 MB): direct B-stream MFMA ------
__global__ __launch_bounds__(512, 2)
void router_mfma(const float* __restrict__ x, const ushort* __restrict__ ws,
                 const float* __restrict__ bias,
                 float* __restrict__ out_scores, float* __restrict__ out_idx,
                 float* __restrict__ counts) {
  __shared__ float logits[64 * 64];
  const int tid  = threadIdx.x;
  const int lane = tid & 63;
  const int wv   = tid >> 6;
  const int wt   = wv & 3;
  const int wk   = wv >> 2;
  const int tok0 = blockIdx.x * 64;
  const int col  = lane & 15;
  const int kq   = lane >> 4;
  const float* xrow = x + (size_t)(tok0 + wt * 16 + col) * DIM + wk * 2048 + 8 * kq;
  const ushort* wsl = ws + (size_t)lane * 8;
  f32x4 acc[4];
#pragma unroll
  for (int et = 0; et < 4; ++et) acc[et] = (f32x4){0.f, 0.f, 0.f, 0.f};
  const int s0 = wk * 64;
  float4 a0c = *(const float4*)(xrow + 0);
  float4 a1c = *(const float4*)(xrow + 4);
  bf16x8 bc[8];
#pragma unroll
  for (int f = 0; f < 8; ++f)
    bc[f] = *(const bf16x8*)(wsl + (size_t)(s0 * 8 + f) * 64 * 8);
#pragma unroll 1
  for (int ls = 0; ls < 64; ls += 2) {
    const int so = s0 + ls + 1;
    float4 a0o = *(const float4*)(xrow + (ls + 1) * 32);
    float4 a1o = *(const float4*)(xrow + (ls + 1) * 32 + 4);
    bf16x8 bo[8];
#pragma unroll
    for (int f = 0; f < 8; ++f)
      bo[f] = *(const bf16x8*)(wsl + (size_t)(so * 8 + f) * 64 * 8);
    {
      bf16x8 ahi, alo;
      split8(a0c, a1c, ahi, alo);
#pragma unroll
      for (int et = 0; et < 4; ++et) {
        acc[et] = __builtin_amdgcn_mfma_f32_16x16x32_bf16(ahi, bc[et * 2 + 0], acc[et], 0, 0, 0);
        acc[et] = __builtin_amdgcn_mfma_f32_16x16x32_bf16(alo, bc[et * 2 + 0], acc[et], 0, 0, 0);
        acc[et] = __builtin_amdgcn_mfma_f32_16x16x32_bf16(ahi, bc[et * 2 + 1], acc[et], 0, 0, 0);
      }
    }
    if (ls + 2 < 64) {
      const int se = s0 + ls + 2;
      a0c = *(const float4*)(xrow + (ls + 2) * 32);
      a1c = *(const float4*)(xrow + (ls + 2) * 32 + 4);
#pragma unroll
      for (int f = 0; f < 8; ++f)
        bc[f] = *(const bf16x8*)(wsl + (size_t)(se * 8 + f) * 64 * 8);
    }
    {
      bf16x8 ahi, alo;
      split8(a0o, a1o, ahi, alo);
#pragma unroll
      for (int et = 0; et < 4; ++et) {
        acc[et] = __builtin_amdgcn_mfma_f32_16x16x32_bf16(ahi, bo[et * 2 + 0], acc[et], 0, 0, 0);
        acc[et] = __builtin_amdgcn_mfma_f32_16x16x32_bf16(alo, bo[et * 2 + 0], acc[et], 0, 0, 0);
        acc[et] = __builtin_amdgcn_mfma_f32_16x16x32_bf16(ahi, bo[et * 2 + 1], acc[et], 0, 0, 0);
      }
    }
  }
  if (wk == 0) {
#pragma unroll
    for (int et = 0; et < 4; ++et)
#pragma unroll
      for (int r = 0; r < 4; ++r) {
        int t = wt * 16 + 4 * kq + r;
        int e = et * 16 + col;
        logits[t * 64 + ((e + t) & 63)] = acc[et][r];
      }
  }
  __syncthreads();
  if (wk == 1) {
#pragma unroll
    for (int et = 0; et < 4; ++et)
#pragma unroll
      for (int r = 0; r < 4; ++r) {
        int t = wt * 16 + 4 * kq + r;
        int e = et * 16 + col;
        logits[t * 64 + ((e + t) & 63)] += acc[et][r];
      }
  }
  __syncthreads();
  if (tid < 64) {
    const int t = tid, gt = tok0 + t;
    float key[8], sv[8]; int idx[8];
#pragma unroll
    for (int j = 0; j < 8; ++j) { key[j] = -1e30f; sv[j] = 0.f; idx[j] = 0; }
    for (int e = 0; e < NE; ++e) {
      float l = logits[t * 64 + ((e + t) & 63)];
      float s = 1.0f / (1.0f + expf(-l));
      float k = s + bias[e];
      float ck = k, cv = s; int ci = e;
#pragma unroll
      for (int j = 0; j < 8; ++j) {
        bool g = ck > key[j];
        float tk = key[j], tv = sv[j]; int ti = idx[j];
        key[j] = g ? ck : tk; sv[j] = g ? cv : tv; idx[j] = g ? ci : ti;
        ck = g ? tk : ck;     cv = g ? tv : cv;    ci = g ? ti : ci;
      }
    }
    float sum = 1e-20f;
#pragma unroll
    for (int j = 0; j < 8; ++j) sum += sv[j];
    float inv = 1.0f / sum;
#pragma unroll
    for (int j = 0; j < 8; ++j) {
      out_scores[gt * 8 + j] = sv[j] * inv;
      out_idx[gt * 8 + j]    = (float)idx[j];
      atomicAdd(&counts[idx[j]], 1.0f);
    }
  }
}

// ---------- R5 proven last-resort fallback (fp32 scalar-w) ----------
constexpr int KSTEP = 32;
constexpr int FNSTEP = DIM / KSTEP;
constexpr int ROWF4 = 9;
constexpr int BUF4  = 64 * ROWF4;

__global__ __launch_bounds__(512, 2)
void router_fallback(const float* __restrict__ x, const float* __restrict__ w,
                     const float* __restrict__ bias,
                     float* __restrict__ out_scores, float* __restrict__ out_idx,
                     float* __restrict__ counts) {
  __shared__ float4 lds4[2 * BUF4];
  float* ldsf = (float*)lds4;
  const int tid  = threadIdx.x;
  const int lane = tid & 63;
  const int eg   = __builtin_amdgcn_readfirstlane(tid >> 6);
  const int tok0 = blockIdx.x * 64;
  const int r0 = tid >> 3, j0 = tid & 7;
  const float* gp = &x[(size_t)(tok0 + r0) * DIM + j0 * 4];
  const int l0 = r0 * ROWF4 + j0;
  float acc[8];
#pragma unroll
  for (int e = 0; e < 8; ++e) acc[e] = 0.f;
  lds4[l0] = *(const float4*)gp;
  __syncthreads();
  const float* wbase = w + (size_t)eg * 8 * DIM;
#pragma unroll 1
  for (int c = 0; c < FNSTEP; ++c) {
    float4 pf;
    if (c + 1 < FNSTEP) pf = *(const float4*)(gp + (c + 1) * KSTEP);
    float xr[KSTEP];
    {
      const float4* xrow = lds4 + (c & 1) * BUF4 + lane * ROWF4;
#pragma unroll
      for (int i = 0; i < 8; ++i) {
        float4 q = xrow[i];
        xr[4 * i + 0] = q.x; xr[4 * i + 1] = q.y;
        xr[4 * i + 2] = q.z; xr[4 * i + 3] = q.w;
      }
    }
#pragma unroll
    for (int e = 0; e < 8; ++e) {
      const float* wr = wbase + e * DIM + c * KSTEP;
#pragma unroll
      for (int k = 0; k < KSTEP; ++k) acc[e] = fmaf(xr[k], wr[k], acc[e]);
    }
    if (c + 1 < FNSTEP) lds4[((c + 1) & 1) * BUF4 + l0] = pf;
    __syncthreads();
  }
#pragma unroll
  for (int j = 0; j < 8; ++j) {
    int e = eg * 8 + j;
    ldsf[lane * 64 + ((e + lane) & 63)] = acc[j];
  }
  __syncthreads();
  if (tid < 64) {
    const int t = tid, gt = tok0 + t;
    float key[8], sv[8]; int idx[8];
#pragma unroll
    for (int j = 0; j < 8; ++j) { key[j] = -1e30f; sv[j] = 0.f; idx[j] = 0; }
    for (int e = 0; e < NE; ++e) {
      float l = ldsf[t * 64 + ((e + t) & 63)];
      float s = 1.0f / (1.0f + expf(-l));
      float k = s + bias[e];
      float ck = k, cv = s; int ci = e;
#pragma unroll
      for (int j = 0; j < 8; ++j) {
        bool g = ck > key[j];
        float tk = key[j], tv = sv[j]; int ti = idx[j];
        key[j] = g ? ck : tk; sv[j] = g ? cv : tv; idx[j] = g ? ci : ti;
        ck = g ? tk : ck;     cv = g ? tv : cv;    ci = g ? ti : ci;
      }
    }
    float sum = 1e-20f;
#pragma unroll
    for (int j = 0; j < 8; ++j) sum += sv[j];
    float inv = 1.0f / sum;
#pragma unroll
    for (int j = 0; j < 8; ++j) {
      out_scores[gt * 8 + j] = sv[j] * inv;
      out_idx[gt * 8 + j]    = (float)idx[j];
      atomicAdd(&counts[idx[j]], 1.0f);
    }
  }
}

extern "C" void kernel_launch(void* const* d_in, const int* in_sizes, int n_in,
                              void* d_out, int out_size, void* d_ws, size_t ws_size,
                              hipStream_t stream) {
  const float* x    = (const float*)d_in[0];
  const float* w    = (const float*)d_in[1];
  const float* bias = (const float*)d_in[2];

  const int ntok = in_sizes[0] / DIM;              // 16384
  float* out        = (float*)d_out;
  float* out_scores = out;
  float* out_idx    = out + ntok * 8;
  float* counts     = out + 2 * ntok * 8;

  hipMemsetAsync(counts, 0, NE * sizeof(float), stream);

  const int    nblk      = ntok / 32;              // 512
  const size_t wsh_bytes = (size_t)nblk * NE * sizeof(float);  // 128 KB
  const size_t need = WSB_BYTES + wsh_bytes;

  if (ws_size >= need && (ntok % 32) == 0) {
    ushort* wsB = (ushort*)d_ws;
    float*  wsH = (float*)((char*)d_ws + WSB_BYTES);
    hipLaunchKernelGGL(pack_w, dim3(256), dim3(256), 0, stream, w, wsB);
    hipLaunchKernelGGL(router_fused, dim3(nblk), dim3(256), 0, stream,
                       x, (const char*)wsB, bias, out_scores, out_idx, wsH);
    hipLaunchKernelGGL(router_k5, dim3(1), dim3(256), 0, stream,
                       wsH, counts, nblk);
  } else if (ws_size >= WSB_BYTES) {
    ushort* wsB = (ushort*)d_ws;
    hipLaunchKernelGGL(pack_w, dim3(256), dim3(256), 0, stream, w, wsB);
    hipLaunchKernelGGL(router_mfma, dim3(ntok / 64), dim3(512), 0, stream,
                       x, wsB, bias, out_scores, out_idx, counts);
  } else {
    hipLaunchKernelGGL(router_fallback, dim3(ntok / 64), dim3(512), 0, stream,
                       x, w, bias, out_scores, out_idx, counts);
  }
}

// Round 18
// 159.340 us; speedup vs baseline: 1.0360x; 1.0360x over previous
//
#include <hip/hip_runtime.h>
#include <math.h>

// TokenChoiceTopKRouter, round 18: break the serial load chain + 2x TLP.
//
// R17 evidence: no-LDS register kernel STILL 1.33 us/iter with VGPR=68 ->
// allocator sank loads to uses (shared dest regs) => serial load->wait->use
// chain ~2400 cyc/iter; with 8 waves/CU that models 128 us exactly.
// R18: (1) 16 waves/CU: K-split (wk) 8-wave 512-thr blocks,
// __launch_bounds__(512,4), grid 512 = 2 blk/CU; R6-proven 2-phase logits
// reduce. (2) 2-slot register double-buffer with sched_barrier(0) pinning
// each LOADS block above the following COMPUTE -> loads for s+1 issue
// back-to-back before COMPUTE(s); compiler's register-tracked waitcnt
// becomes a real counted vmcnt. Proven numerics (bf16 hi/lo 3-pass,
// absmax 50), proven epilogue + wsH/k5 histogram.

constexpr int DIM = 4096;
constexpr int NE  = 64;
constexpr size_t WSB_BYTES = 1048576;            // packed B stream (1 MB)

typedef __attribute__((ext_vector_type(8))) short bf16x8;
typedef __attribute__((ext_vector_type(4))) float f32x4;

// ---------- k1: pack w into hi/lo B-fragment stream (R6/R10-proven) ---------
// 16B-unit u = sl*512 + f*64 + lane (sl = 32k step 0..127, f = et*2 + hl).
// Content: e = et*16 + (lane&15), k = sl*32 + 8*(lane>>4) (+j), hi/lo bf16.
__global__ void pack_w(const float* __restrict__ w, ushort* __restrict__ wsB) {
  const int u  = blockIdx.x * 256 + threadIdx.x;   // 65536 units
  const int l  = u & 63;
  const int f  = (u >> 6) & 7;
  const int sl = u >> 9;                           // 0..127
  const int et = f >> 1, hl = f & 1;
  const int e  = et * 16 + (l & 15);
  const int k  = sl * 32 + 8 * (l >> 4);
  const float* src = w + (size_t)e * DIM + k;
  ushort v[8];
#pragma unroll
  for (int j = 0; j < 8; ++j) {
    float xv = src[j];
    unsigned xb = __float_as_uint(xv);
    unsigned hb = xb & 0xffff0000u;                // exact hi (truncation)
    if (hl == 0) {
      v[j] = (ushort)(hb >> 16);
    } else {
      float lf = xv - __uint_as_float(hb);
      unsigned lb = __float_as_uint(lf);
      lb = lb + 0x7fffu + ((lb >> 16) & 1u);       // RNE to bf16
      v[j] = (ushort)(lb >> 16);
    }
  }
  ushort* d = wsB + (size_t)u * 8;
#pragma unroll
  for (int j = 0; j < 8; ++j) d[j] = v[j];
}

// ---------- shared helper: two float4 -> hi/lo bf16x8 ----------
__device__ __forceinline__ void split8(const float4& a0, const float4& a1,
                                       bf16x8& ahi, bf16x8& alo) {
  float av[8] = {a0.x, a0.y, a0.z, a0.w, a1.x, a1.y, a1.z, a1.w};
#pragma unroll
  for (int j = 0; j < 8; ++j) {
    unsigned xb = __float_as_uint(av[j]);
    unsigned hb = xb & 0xffff0000u;
    float lf = av[j] - __uint_as_float(hb);
    unsigned lb = __float_as_uint(lf);
    lb = lb + 0x7fffu + ((lb >> 16) & 1u);
    ahi[j] = (short)(hb >> 16);
    alo[j] = (short)(lb >> 16);
  }
}

// ---------- fused main kernel: register pipeline, 16 waves/CU ----------
// 512 blocks x 512 thr (8 waves = tt(2) x eh(2) x wk(2)), 2 blocks/CU.
// Wave: 16 tok x 32 exp x K/2 (2048k = 64 steps of 32k). Per step: 2 A-loads
// (32 B of one x row/lane) + 4 B-frag loads (lane-major dwordx4 from the
// L2-resident packed stream) -> split -> 6 MFMA. Two named register slots,
// LOADS(s+1) pinned above COMPUTE(s) by sched_barrier(0).
__global__ __launch_bounds__(512, 4)
void router_fused(const float* __restrict__ x, const char* __restrict__ wsB,
                  const float* __restrict__ bias,
                  float* __restrict__ out_scores, float* __restrict__ out_idx,
                  float* __restrict__ wsH) {
  __shared__ float logits[32 * 64];
  __shared__ float hist[NE];
  const int tid  = threadIdx.x;
  const int wv   = tid >> 6;
  const int lane = tid & 63;
  const int tt   = wv & 1;            // token tile 0..1
  const int eh   = (wv >> 1) & 1;     // expert half 0..1
  const int wk   = wv >> 2;           // K half 0..1
  const int col  = lane & 15;
  const int kq   = lane >> 4;
  const int tok0 = blockIdx.x * 32;

  // A source: lane's row, k = wk*2048 + s*32 + kq*8 .. +8
  const float* xp = x + (size_t)(tok0 + tt * 16 + col) * DIM + wk * 2048 + kq * 8;
  // B source: unit (wk*64+s)*512 + (eh*4+i)*64 + lane
  const bf16x8* bpe = (const bf16x8*)wsB + (size_t)wk * 64 * 512 +
                      (size_t)eh * 4 * 64 + lane;

  f32x4 acc[2];
  acc[0] = (f32x4){0.f, 0.f, 0.f, 0.f};
  acc[1] = (f32x4){0.f, 0.f, 0.f, 0.f};

#define LOADS(s, XA, XB, B0, B1, B2, B3)                                     \
  do {                                                                      \
    XA = *(const float4*)(xp + (size_t)(s) * 32);                           \
    XB = *(const float4*)(xp + (size_t)(s) * 32 + 4);                       \
    B0 = bpe[(size_t)(s) * 512 + 0];                                        \
    B1 = bpe[(size_t)(s) * 512 + 64];                                       \
    B2 = bpe[(size_t)(s) * 512 + 128];                                      \
    B3 = bpe[(size_t)(s) * 512 + 192];                                      \
  } while (0)

#define COMPUTE(XA, XB, B0, B1, B2, B3)                                      \
  do {                                                                      \
    bf16x8 ahi, alo;                                                        \
    float4 xa_ = XA, xb_ = XB;                                              \
    split8(xa_, xb_, ahi, alo);                                             \
    acc[0] = __builtin_amdgcn_mfma_f32_16x16x32_bf16(ahi, B0, acc[0], 0, 0, 0); \
    acc[0] = __builtin_amdgcn_mfma_f32_16x16x32_bf16(alo, B0, acc[0], 0, 0, 0); \
    acc[0] = __builtin_amdgcn_mfma_f32_16x16x32_bf16(ahi, B1, acc[0], 0, 0, 0); \
    acc[1] = __builtin_amdgcn_mfma_f32_16x16x32_bf16(ahi, B2, acc[1], 0, 0, 0); \
    acc[1] = __builtin_amdgcn_mfma_f32_16x16x32_bf16(alo, B2, acc[1], 0, 0, 0); \
    acc[1] = __builtin_amdgcn_mfma_f32_16x16x32_bf16(ahi, B3, acc[1], 0, 0, 0); \
  } while (0)

  // two named register slots A/B; depth-1 prefetch, pinned issue order
  float4 xaA, xbA, xaB, xbB;
  bf16x8 bA0, bA1, bA2, bA3, bB0, bB1, bB2, bB3;

  LOADS(0, xaA, xbA, bA0, bA1, bA2, bA3);
  __builtin_amdgcn_sched_barrier(0);

#pragma unroll 1
  for (int s = 0; s < 64; s += 2) {
    LOADS(s + 1, xaB, xbB, bB0, bB1, bB2, bB3);      // s+1 <= 63 always
    __builtin_amdgcn_sched_barrier(0);               // loads stay above
    COMPUTE(xaA, xbA, bA0, bA1, bA2, bA3);
    __builtin_amdgcn_sched_barrier(0);
    if (s + 2 < 64) {
      LOADS(s + 2, xaA, xbA, bA0, bA1, bA2, bA3);
      __builtin_amdgcn_sched_barrier(0);
    }
    COMPUTE(xaB, xbB, bB0, bB1, bB2, bB3);
    __builtin_amdgcn_sched_barrier(0);
  }
#undef LOADS
#undef COMPUTE

  // ---- epilogue: 2-phase K-half reduce into rotated logits (R6-proven) ----
  if (tid < 64) hist[tid] = 0.f;
  // D layout (m89/R6-verified): e-col = et*16+col, token-row = 4*kq+r
  if (wk == 0) {
#pragma unroll
    for (int et2 = 0; et2 < 2; ++et2)
#pragma unroll
      for (int rr = 0; rr < 4; ++rr) {
        int t = tt * 16 + 4 * kq + rr;
        int e = eh * 32 + et2 * 16 + col;
        logits[t * 64 + ((e + t) & 63)] = acc[et2][rr];
      }
  }
  __syncthreads();
  if (wk == 1) {
#pragma unroll
    for (int et2 = 0; et2 < 2; ++et2)
#pragma unroll
      for (int rr = 0; rr < 4; ++rr) {
        int t = tt * 16 + 4 * kq + rr;
        int e = eh * 32 + et2 * 16 + col;
        logits[t * 64 + ((e + t) & 63)] += acc[et2][rr];
      }
  }
  __syncthreads();

  // ---- sigmoid + biased top-8 + normalize + LDS hist (proven tail) ----
  if (tid < 32) {
    const int t = tid, gt = tok0 + t;
    float key[8], sv[8];
    int   idx[8];
#pragma unroll
    for (int j = 0; j < 8; ++j) { key[j] = -1e30f; sv[j] = 0.f; idx[j] = 0; }

    for (int e = 0; e < NE; ++e) {
      float l = logits[t * 64 + ((e + t) & 63)];
      float s = 1.0f / (1.0f + expf(-l));
      float k = s + bias[e];
      // bubble-insert; strict > keeps lower index on ties (lax.top_k order)
      float ck = k, cv = s; int ci = e;
#pragma unroll
      for (int j = 0; j < 8; ++j) {
        bool g = ck > key[j];
        float tk = key[j], tv = sv[j]; int ti = idx[j];
        key[j] = g ? ck : tk; sv[j] = g ? cv : tv; idx[j] = g ? ci : ti;
        ck = g ? tk : ck;     cv = g ? tv : cv;    ci = g ? ti : ci;
      }
    }

    float sum = 1e-20f;
#pragma unroll
    for (int j = 0; j < 8; ++j) sum += sv[j];
    float inv = 1.0f / sum;
#pragma unroll
    for (int j = 0; j < 8; ++j) {
      out_scores[gt * 8 + j] = sv[j] * inv;
      out_idx[gt * 8 + j]    = (float)idx[j];
      atomicAdd(&hist[idx[j]], 1.0f);      // LDS atomic
    }
  }
  __syncthreads();
  if (tid < 64) wsH[(size_t)blockIdx.x * NE + tid] = hist[tid];
}

// ---------- k5: reduce per-block histograms -> counts (no atomics) ----------
__global__ __launch_bounds__(256)
void router_k5(const float* __restrict__ wsH, float* __restrict__ counts,
               int nblk) {
  __shared__ float part[256];
  const int e = threadIdx.x & 63, p = threadIdx.x >> 6;
  float s = 0.f;
  for (int b = p; b < nblk; b += 4) s += wsH[(size_t)b * NE + e];
  part[p * 64 + e] = s;
  __syncthreads();
  if (threadIdx.x < 64)
    counts[e] = part[e] + part[64 + e] + part[128 + e] + part[192 + e];
}

// ---------- R6 proven mid-fallback (ws >= 1 MB): direct B-stream MFMA ------
__global__ __launch_bounds__(512, 2)
void router_mfma(const float* __restrict__ x, const ushort* __restrict__ ws,
                 const float* __restrict__ bias,
                 float* __restrict__ out_scores, float* __restrict__ out_idx,
                 float* __restrict__ counts) {
  __shared__ float logits[64 * 64];
  const int tid  = threadIdx.x;
  const int lane = tid & 63;
  const int wv   = tid >> 6;
  const int wt   = wv & 3;
  const int wk   = wv >> 2;
  const int tok0 = blockIdx.x * 64;
  const int col  = lane & 15;
  const int kq   = lane >> 4;
  const float* xrow = x + (size_t)(tok0 + wt * 16 + col) * DIM + wk * 2048 + 8 * kq;
  const ushort* wsl = ws + (size_t)lane * 8;
  f32x4 acc[4];
#pragma unroll
  for (int et = 0; et < 4; ++et) acc[et] = (f32x4){0.f, 0.f, 0.f, 0.f};
  const int s0 = wk * 64;
  float4 a0c = *(const float4*)(xrow + 0);
  float4 a1c = *(const float4*)(xrow + 4);
  bf16x8 bc[8];
#pragma unroll
  for (int f = 0; f < 8; ++f)
    bc[f] = *(const bf16x8*)(wsl + (size_t)(s0 * 8 + f) * 64 * 8);
#pragma unroll 1
  for (int ls = 0; ls < 64; ls += 2) {
    const int so = s0 + ls + 1;
    float4 a0o = *(const float4*)(xrow + (ls + 1) * 32);
    float4 a1o = *(const float4*)(xrow + (ls + 1) * 32 + 4);
    bf16x8 bo[8];
#pragma unroll
    for (int f = 0; f < 8; ++f)
      bo[f] = *(const bf16x8*)(wsl + (size_t)(so * 8 + f) * 64 * 8);
    {
      bf16x8 ahi, alo;
      split8(a0c, a1c, ahi, alo);
#pragma unroll
      for (int et = 0; et < 4; ++et) {
        acc[et] = __builtin_amdgcn_mfma_f32_16x16x32_bf16(ahi, bc[et * 2 + 0], acc[et], 0, 0, 0);
        acc[et] = __builtin_amdgcn_mfma_f32_16x16x32_bf16(alo, bc[et * 2 + 0], acc[et], 0, 0, 0);
        acc[et] = __builtin_amdgcn_mfma_f32_16x16x32_bf16(ahi, bc[et * 2 + 1], acc[et], 0, 0, 0);
      }
    }
    if (ls + 2 < 64) {
      const int se = s0 + ls + 2;
      a0c = *(const float4*)(xrow + (ls + 2) * 32);
      a1c = *(const float4*)(xrow + (ls + 2) * 32 + 4);
#pragma unroll
      for (int f = 0; f < 8; ++f)
        bc[f] = *(const bf16x8*)(wsl + (size_t)(se * 8 + f) * 64 * 8);
    }
    {
      bf16x8 ahi, alo;
      split8(a0o, a1o, ahi, alo);
#pragma unroll
      for (int et = 0; et < 4; ++et) {
        acc[et] = __builtin_amdgcn_mfma_f32_16x16x32_bf16(ahi, bo[et * 2 + 0], acc[et], 0, 0, 0);
        acc[et] = __builtin_amdgcn_mfma_f32_16x16x32_bf16(alo, bo[et * 2 + 0], acc[et], 0, 0, 0);
        acc[et] = __builtin_amdgcn_mfma_f32_16x16x32_bf16(ahi, bo[et * 2 + 1], acc[et], 0, 0, 0);
      }
    }
  }
  if (wk == 0) {
#pragma unroll
    for (int et = 0; et < 4; ++et)
#pragma unroll
      for (int r = 0; r < 4; ++r) {
        int t = wt * 16 + 4 * kq + r;
        int e = et * 16 + col;
        logits[t * 64 + ((e + t) & 63)] = acc[et][r];
      }
  }
  __syncthreads();
  if (wk == 1) {
#pragma unroll
    for (int et = 0; et < 4; ++et)
#pragma unroll
      for (int r = 0; r < 4; ++r) {
        int t = wt * 16 + 4 * kq + r;
        int e = et * 16 + col;
        logits[t * 64 + ((e + t) & 63)] += acc[et][r];
      }
  }
  __syncthreads();
  if (tid < 64) {
    const int t = tid, gt = tok0 + t;
    float key[8], sv[8]; int idx[8];
#pragma unroll
    for (int j = 0; j < 8; ++j) { key[j] = -1e30f; sv[j] = 0.f; idx[j] = 0; }
    for (int e = 0; e < NE; ++e) {
      float l = logits[t * 64 + ((e + t) & 63)];
      float s = 1.0f / (1.0f + expf(-l));
      float k = s + bias[e];
      float ck = k, cv = s; int ci = e;
#pragma unroll
      for (int j = 0; j < 8; ++j) {
        bool g = ck > key[j];
        float tk = key[j], tv = sv[j]; int ti = idx[j];
        key[j] = g ? ck : tk; sv[j] = g ? cv : tv; idx[j] = g ? ci : ti;
        ck = g ? tk : ck;     cv = g ? tv : cv;    ci = g ? ti : ci;
      }
    }
    float sum = 1e-20f;
#pragma unroll
    for (int j = 0; j < 8; ++j) sum += sv[j];
    float inv = 1.0f / sum;
#pragma unroll
    for (int j = 0; j < 8; ++j) {
      out_scores[gt * 8 + j] = sv[j] * inv;
      out_idx[gt * 8 + j]    = (float)idx[j];
      atomicAdd(&counts[idx[j]], 1.0f);
    }
  }
}

// ---------- R5 proven last-resort fallback (fp32 scalar-w) ----------
constexpr int KSTEP = 32;
constexpr int FNSTEP = DIM / KSTEP;
constexpr int ROWF4 = 9;
constexpr int BUF4  = 64 * ROWF4;

__global__ __launch_bounds__(512, 2)
void router_fallback(const float* __restrict__ x, const float* __restrict__ w,
                     const float* __restrict__ bias,
                     float* __restrict__ out_scores, float* __restrict__ out_idx,
                     float* __restrict__ counts) {
  __shared__ float4 lds4[2 * BUF4];
  float* ldsf = (float*)lds4;
  const int tid  = threadIdx.x;
  const int lane = tid & 63;
  const int eg   = __builtin_amdgcn_readfirstlane(tid >> 6);
  const int tok0 = blockIdx.x * 64;
  const int r0 = tid >> 3, j0 = tid & 7;
  const float* gp = &x[(size_t)(tok0 + r0) * DIM + j0 * 4];
  const int l0 = r0 * ROWF4 + j0;
  float acc[8];
#pragma unroll
  for (int e = 0; e < 8; ++e) acc[e] = 0.f;
  lds4[l0] = *(const float4*)gp;
  __syncthreads();
  const float* wbase = w + (size_t)eg * 8 * DIM;
#pragma unroll 1
  for (int c = 0; c < FNSTEP; ++c) {
    float4 pf;
    if (c + 1 < FNSTEP) pf = *(const float4*)(gp + (c + 1) * KSTEP);
    float xr[KSTEP];
    {
      const float4* xrow = lds4 + (c & 1) * BUF4 + lane * ROWF4;
#pragma unroll
      for (int i = 0; i < 8; ++i) {
        float4 q = xrow[i];
        xr[4 * i + 0] = q.x; xr[4 * i + 1] = q.y;
        xr[4 * i + 2] = q.z; xr[4 * i + 3] = q.w;
      }
    }
#pragma unroll
    for (int e = 0; e < 8; ++e) {
      const float* wr = wbase + e * DIM + c * KSTEP;
#pragma unroll
      for (int k = 0; k < KSTEP; ++k) acc[e] = fmaf(xr[k], wr[k], acc[e]);
    }
    if (c + 1 < FNSTEP) lds4[((c + 1) & 1) * BUF4 + l0] = pf;
    __syncthreads();
  }
#pragma unroll
  for (int j = 0; j < 8; ++j) {
    int e = eg * 8 + j;
    ldsf[lane * 64 + ((e + lane) & 63)] = acc[j];
  }
  __syncthreads();
  if (tid < 64) {
    const int t = tid, gt = tok0 + t;
    float key[8], sv[8]; int idx[8];
#pragma unroll
    for (int j = 0; j < 8; ++j) { key[j] = -1e30f; sv[j] = 0.f; idx[j] = 0; }
    for (int e = 0; e < NE; ++e) {
      float l = ldsf[t * 64 + ((e + t) & 63)];
      float s = 1.0f / (1.0f + expf(-l));
      float k = s + bias[e];
      float ck = k, cv = s; int ci = e;
#pragma unroll
      for (int j = 0; j < 8; ++j) {
        bool g = ck > key[j];
        float tk = key[j], tv = sv[j]; int ti = idx[j];
        key[j] = g ? ck : tk; sv[j] = g ? cv : tv; idx[j] = g ? ci : ti;
        ck = g ? tk : ck;     cv = g ? tv : cv;    ci = g ? ti : ci;
      }
    }
    float sum = 1e-20f;
#pragma unroll
    for (int j = 0; j < 8; ++j) sum += sv[j];
    float inv = 1.0f / sum;
#pragma unroll
    for (int j = 0; j < 8; ++j) {
      out_scores[gt * 8 + j] = sv[j] * inv;
      out_idx[gt * 8 + j]    = (float)idx[j];
      atomicAdd(&counts[idx[j]], 1.0f);
    }
  }
}

extern "C" void kernel_launch(void* const* d_in, const int* in_sizes, int n_in,
                              void* d_out, int out_size, void* d_ws, size_t ws_size,
                              hipStream_t stream) {
  const float* x    = (const float*)d_in[0];
  const float* w    = (const float*)d_in[1];
  const float* bias = (const float*)d_in[2];

  const int ntok = in_sizes[0] / DIM;              // 16384
  float* out        = (float*)d_out;
  float* out_scores = out;
  float* out_idx    = out + ntok * 8;
  float* counts     = out + 2 * ntok * 8;

  hipMemsetAsync(counts, 0, NE * sizeof(float), stream);

  const int    nblk      = ntok / 32;              // 512
  const size_t wsh_bytes = (size_t)nblk * NE * sizeof(float);  // 128 KB
  const size_t need = WSB_BYTES + wsh_bytes;

  if (ws_size >= need && (ntok % 32) == 0) {
    ushort* wsB = (ushort*)d_ws;
    float*  wsH = (float*)((char*)d_ws + WSB_BYTES);
    hipLaunchKernelGGL(pack_w, dim3(256), dim3(256), 0, stream, w, wsB);
    hipLaunchKernelGGL(router_fused, dim3(nblk), dim3(512), 0, stream,
                       x, (const char*)wsB, bias, out_scores, out_idx, wsH);
    hipLaunchKernelGGL(router_k5, dim3(1), dim3(256), 0, stream,
                       wsH, counts, nblk);
  } else if (ws_size >= WSB_BYTES) {
    ushort* wsB = (ushort*)d_ws;
    hipLaunchKernelGGL(pack_w, dim3(256), dim3(256), 0, stream, w, wsB);
    hipLaunchKernelGGL(router_mfma, dim3(ntok / 64), dim3(512), 0, stream,
                       x, wsB, bias, out_scores, out_idx, counts);
  } else {
    hipLaunchKernelGGL(router_fallback, dim3(ntok / 64), dim3(512), 0, stream,
                       x, w, bias, out_scores, out_idx, counts);
  }
}

// Round 19
// 116.821 us; speedup vs baseline: 1.4131x; 1.3640x over previous
//
#include <hip/hip_runtime.h>
#include <math.h>

// TokenChoiceTopKRouter, round 19: contiguous 512-B x reads, reg-staged
// LDS scatter (no global_load_lds).
//
// R10-R18 invariant: ~flat 120-170 us across barrier/no-barrier, LDS/no-LDS,
// 8-16 waves, depth 1-3 -> the common factor is x read in 128-256 B fragments
// at 16 KB row stride (forced by MFMA fragment layout / global_load_lds's
// wave-uniform dest). R19 tests the granularity theory: stage x global->VGPR
// ->ds_write with 512-B contiguous segments (8 instr x 2 rows x 512 B per
// wave per 128-k chunk), scatter into 4x the byte-identical R16-proven 32-k
// sub-tile layout (same XOR swizzle). Wave-private 2-buf, zero barriers,
// asm ds_read + lgkmcnt(0) + sched_barrier (rule #18); same-wave DS ordering
// makes write->read safe. B direct-global (L2-resident). launch_bounds(256,2)
// -> 256-VGPR budget. k5 parallelized to 64 blocks.
// Proven numerics (bf16 hi/lo 3-pass, absmax 50) + proven epilogue.

constexpr int DIM = 4096;
constexpr int NE  = 64;
constexpr int NCH = 32;                          // 128-k chunks
constexpr size_t WSB_BYTES = 1048576;            // packed B stream (1 MB)

typedef __attribute__((ext_vector_type(8))) short bf16x8;
typedef __attribute__((ext_vector_type(4))) float f32x4;

__device__ __forceinline__ f32x4 dsr_f4(const char* p) {
  f32x4 r;
  asm volatile("ds_read_b128 %0, %1"
               : "=v"(r)
               : "v"((const __attribute__((address_space(3))) char*)p));
  return r;
}
__device__ __forceinline__ void dsw_f4(char* p, f32x4 v) {
  asm volatile("ds_write_b128 %0, %1"
               :
               : "v"((__attribute__((address_space(3))) char*)p), "v"(v)
               : "memory");
}

// ---------- k1: pack w into hi/lo B-fragment stream (R6/R10-proven) ---------
// 16B-unit u = sl*512 + f*64 + lane (sl = 32k step 0..127, f = et*2 + hl).
// Content: e = et*16 + (lane&15), k = sl*32 + 8*(lane>>4) (+j), hi/lo bf16.
__global__ void pack_w(const float* __restrict__ w, ushort* __restrict__ wsB) {
  const int u  = blockIdx.x * 256 + threadIdx.x;   // 65536 units
  const int l  = u & 63;
  const int f  = (u >> 6) & 7;
  const int sl = u >> 9;                           // 0..127
  const int et = f >> 1, hl = f & 1;
  const int e  = et * 16 + (l & 15);
  const int k  = sl * 32 + 8 * (l >> 4);
  const float* src = w + (size_t)e * DIM + k;
  ushort v[8];
#pragma unroll
  for (int j = 0; j < 8; ++j) {
    float xv = src[j];
    unsigned xb = __float_as_uint(xv);
    unsigned hb = xb & 0xffff0000u;                // exact hi (truncation)
    if (hl == 0) {
      v[j] = (ushort)(hb >> 16);
    } else {
      float lf = xv - __uint_as_float(hb);
      unsigned lb = __float_as_uint(lf);
      lb = lb + 0x7fffu + ((lb >> 16) & 1u);       // RNE to bf16
      v[j] = (ushort)(lb >> 16);
    }
  }
  ushort* d = wsB + (size_t)u * 8;
#pragma unroll
  for (int j = 0; j < 8; ++j) d[j] = v[j];
}

// ---------- shared helper: two f32x4 -> hi/lo bf16x8 ----------
__device__ __forceinline__ void split8v(const f32x4& a0, const f32x4& a1,
                                        bf16x8& ahi, bf16x8& alo) {
#pragma unroll
  for (int j = 0; j < 8; ++j) {
    float av = (j < 4) ? a0[j] : a1[j - 4];
    unsigned xb = __float_as_uint(av);
    unsigned hb = xb & 0xffff0000u;
    float lf = av - __uint_as_float(hb);
    unsigned lb = __float_as_uint(lf);
    lb = lb + 0x7fffu + ((lb >> 16) & 1u);
    ahi[j] = (short)(hb >> 16);
    alo[j] = (short)(lb >> 16);
  }
}

// ---------- fused main kernel ----------
// 512 blocks x 256 thr (4 waves = tt(2) x eh(2)), 2 blocks/CU.
// Wave: 16 tok x 32 exp x full K; 32 chunks of 128 k (4 x 32-k sub-steps).
// Wave-private LDS 16 KB at wv*16384: buf q=(c&1)*8192:
//   [sub-step ss(4) x 2048][row(16) x 128][unit(8) x 16, swizzled u^(row&7)]
// x staged global->reg->ds_write: 8 loads/chunk, each 2 rows x 512 B CONTIG.
// A-frag reads identical to R16 (proven). B direct-global lane-major.
__global__ __launch_bounds__(256, 2)
void router_fused(const float* __restrict__ x, const char* __restrict__ wsB,
                  const float* __restrict__ bias,
                  float* __restrict__ out_scores, float* __restrict__ out_idx,
                  float* __restrict__ wsH) {
  __shared__ char lds[65536];
  const int tid  = threadIdx.x;
  const int wv   = tid >> 6;
  const int lane = tid & 63;
  const int tt   = wv & 1;            // token tile 0..1
  const int eh   = wv >> 1;           // expert half 0..1
  const int col  = lane & 15;
  const int kq   = lane >> 4;
  const int tok0 = blockIdx.x * 32;

  char* wreg = lds + wv * 16384;      // this wave's private region

  // staging map: unit u = i*64+lane (i=0..7): row=u>>5 (0..15), j=u&31.
  // global: 2 rows x 512 B contiguous per instruction.
  // LDS: ss=j>>3, uu=j&7 -> ss*2048 + row*128 + (uu^(row&7))*16.
  const int srow = lane >> 5;             // + 2*i
  const int sj   = lane & 31;
  const int sss  = sj >> 3;
  const int suu  = sj & 7;
  const float* gx = x + (size_t)(tok0 + tt * 16) * DIM + sj * 4;  // +row*DIM +c*128
  int ldst[8];
#pragma unroll
  for (int i = 0; i < 8; ++i) {
    int row = srow + 2 * i;
    ldst[i] = sss * 2048 + row * 128 + ((suu ^ (row & 7)) * 16);
  }

  // B source: unit (c*4+s4)*512 + (eh*4+f)*64 + lane
  const bf16x8* bpe = (const bf16x8*)wsB + (size_t)eh * 4 * 64 + lane;

  f32x4 acc[2];
  acc[0] = (f32x4){0.f, 0.f, 0.f, 0.f};
  acc[1] = (f32x4){0.f, 0.f, 0.f, 0.f};

  const int am = col & 7;
  const int u0 = (0 * 2 + 0);  // per-s4 below

  // prologue: load chunk 0 stage regs
  f32x4 sx[8];
#pragma unroll
  for (int i = 0; i < 8; ++i)
    sx[i] = *(const f32x4*)(gx + (size_t)(srow + 2 * i) * DIM);

#pragma unroll 1
  for (int c = 0; c < NCH; ++c) {
    char* bq = wreg + (c & 1) * 8192;
    // 1. scatter chunk c stage regs into LDS (2-way banks, free)
#pragma unroll
    for (int i = 0; i < 8; ++i) dsw_f4(bq + ldst[i], sx[i]);
    __builtin_amdgcn_sched_barrier(0);

    // 2. issue chunk c+1 global x loads (contiguous 512-B segments)
    if (c + 1 < NCH) {
#pragma unroll
      for (int i = 0; i < 8; ++i)
        sx[i] = *(const f32x4*)(gx + (size_t)(srow + 2 * i) * DIM +
                                (c + 1) * 128);
    }
    __builtin_amdgcn_sched_barrier(0);

    // 3. B frags for the 4 sub-steps (direct global, compiler-scheduled)
    bf16x8 bf[16];
#pragma unroll
    for (int s4 = 0; s4 < 4; ++s4)
#pragma unroll
      for (int f = 0; f < 4; ++f)
        bf[s4 * 4 + f] = bpe[(size_t)(c * 4 + s4) * 512 + f * 64];

    // 4. compute 4 sub-steps from LDS (same-wave DS ordering: writes done)
#pragma unroll
    for (int s4 = 0; s4 < 4; ++s4) {
      const char* la = bq + s4 * 2048 + col * 128;
      f32x4 a0 = dsr_f4(la + ((kq * 2 + 0) ^ am) * 16);
      f32x4 a1 = dsr_f4(la + ((kq * 2 + 1) ^ am) * 16);
      asm volatile("s_waitcnt lgkmcnt(0)" ::: "memory");
      __builtin_amdgcn_sched_barrier(0);  // rule #18
      bf16x8 ahi, alo;
      split8v(a0, a1, ahi, alo);
      acc[0] = __builtin_amdgcn_mfma_f32_16x16x32_bf16(ahi, bf[s4 * 4 + 0], acc[0], 0, 0, 0);
      acc[0] = __builtin_amdgcn_mfma_f32_16x16x32_bf16(alo, bf[s4 * 4 + 0], acc[0], 0, 0, 0);
      acc[0] = __builtin_amdgcn_mfma_f32_16x16x32_bf16(ahi, bf[s4 * 4 + 1], acc[0], 0, 0, 0);
      acc[1] = __builtin_amdgcn_mfma_f32_16x16x32_bf16(ahi, bf[s4 * 4 + 2], acc[1], 0, 0, 0);
      acc[1] = __builtin_amdgcn_mfma_f32_16x16x32_bf16(alo, bf[s4 * 4 + 2], acc[1], 0, 0, 0);
      acc[1] = __builtin_amdgcn_mfma_f32_16x16x32_bf16(ahi, bf[s4 * 4 + 3], acc[1], 0, 0, 0);
    }
  }

  // ---- epilogue: full-K logits, 16 tok x 32 exp per wave (R16-proven) ----
  __syncthreads();                         // only barrier; LDS reusable
  float* logits = (float*)lds;             // 8 KB (32 x 64)
  float* hist   = (float*)(lds + 8192);    // 256 B
  if (tid < 64) hist[tid] = 0.f;
  // D layout (m89/R6-verified): e-col = et*16+col, token-row = 4*kq+r
#pragma unroll
  for (int et2 = 0; et2 < 2; ++et2)
#pragma unroll
    for (int rr = 0; rr < 4; ++rr) {
      int t = tt * 16 + 4 * kq + rr;
      int e = eh * 32 + et2 * 16 + col;
      logits[t * 64 + ((e + t) & 63)] = acc[et2][rr];
    }
  __syncthreads();

  // ---- sigmoid + biased top-8 + normalize + LDS hist (proven tail) ----
  if (tid < 32) {
    const int t = tid, gt = tok0 + t;
    float key[8], sv[8];
    int   idx[8];
#pragma unroll
    for (int j = 0; j < 8; ++j) { key[j] = -1e30f; sv[j] = 0.f; idx[j] = 0; }

    for (int e = 0; e < NE; ++e) {
      float l = logits[t * 64 + ((e + t) & 63)];
      float s = 1.0f / (1.0f + expf(-l));
      float k = s + bias[e];
      // bubble-insert; strict > keeps lower index on ties (lax.top_k order)
      float ck = k, cv = s; int ci = e;
#pragma unroll
      for (int j = 0; j < 8; ++j) {
        bool g = ck > key[j];
        float tk = key[j], tv = sv[j]; int ti = idx[j];
        key[j] = g ? ck : tk; sv[j] = g ? cv : tv; idx[j] = g ? ci : ti;
        ck = g ? tk : ck;     cv = g ? tv : cv;    ci = g ? ti : ci;
      }
    }

    float sum = 1e-20f;
#pragma unroll
    for (int j = 0; j < 8; ++j) sum += sv[j];
    float inv = 1.0f / sum;
#pragma unroll
    for (int j = 0; j < 8; ++j) {
      out_scores[gt * 8 + j] = sv[j] * inv;
      out_idx[gt * 8 + j]    = (float)idx[j];
      atomicAdd(&hist[idx[j]], 1.0f);      // LDS atomic
    }
  }
  __syncthreads();
  if (tid < 64) wsH[(size_t)blockIdx.x * NE + tid] = hist[tid];
}

// ---------- k5: reduce per-block histograms (64 blocks, parallel) ----------
__global__ __launch_bounds__(64)
void router_k5(const float* __restrict__ wsH, float* __restrict__ counts,
               int nblk) {
  const int e = blockIdx.x;               // expert
  const int i = threadIdx.x;              // 0..63
  float s = 0.f;
  for (int b = i; b < nblk; b += 64) s += wsH[(size_t)b * NE + e];
#pragma unroll
  for (int off = 32; off >= 1; off >>= 1) s += __shfl_down(s, off, 64);
  if (i == 0) counts[e] = s;
}

// ---------- helper kept for fallbacks ----------
__device__ __forceinline__ void split8(const float4& a0, const float4& a1,
                                       bf16x8& ahi, bf16x8& alo) {
  float av[8] = {a0.x, a0.y, a0.z, a0.w, a1.x, a1.y, a1.z, a1.w};
#pragma unroll
  for (int j = 0; j < 8; ++j) {
    unsigned xb = __float_as_uint(av[j]);
    unsigned hb = xb & 0xffff0000u;
    float lf = av[j] - __uint_as_float(hb);
    unsigned lb = __float_as_uint(lf);
    lb = lb + 0x7fffu + ((lb >> 16) & 1u);
    ahi[j] = (short)(hb >> 16);
    alo[j] = (short)(lb >> 16);
  }
}

// ---------- R6 proven mid-fallback (ws >= 1 MB): direct B-stream MFMA ------
__global__ __launch_bounds__(512, 2)
void router_mfma(const float* __restrict__ x, const ushort* __restrict__ ws,
                 const float* __restrict__ bias,
                 float* __restrict__ out_scores, float* __restrict__ out_idx,
                 float* __restrict__ counts) {
  __shared__ float logits[64 * 64];
  const int tid  = threadIdx.x;
  const int lane = tid & 63;
  const int wv   = tid >> 6;
  const int wt   = wv & 3;
  const int wk   = wv >> 2;
  const int tok0 = blockIdx.x * 64;
  const int col  = lane & 15;
  const int kq   = lane >> 4;
  const float* xrow = x + (size_t)(tok0 + wt * 16 + col) * DIM + wk * 2048 + 8 * kq;
  const ushort* wsl = ws + (size_t)lane * 8;
  f32x4 acc[4];
#pragma unroll
  for (int et = 0; et < 4; ++et) acc[et] = (f32x4){0.f, 0.f, 0.f, 0.f};
  const int s0 = wk * 64;
  float4 a0c = *(const float4*)(xrow + 0);
  float4 a1c = *(const float4*)(xrow + 4);
  bf16x8 bc[8];
#pragma unroll
  for (int f = 0; f < 8; ++f)
    bc[f] = *(const bf16x8*)(wsl + (size_t)(s0 * 8 + f) * 64 * 8);
#pragma unroll 1
  for (int ls = 0; ls < 64; ls += 2) {
    const int so = s0 + ls + 1;
    float4 a0o = *(const float4*)(xrow + (ls + 1) * 32);
    float4 a1o = *(const float4*)(xrow + (ls + 1) * 32 + 4);
    bf16x8 bo[8];
#pragma unroll
    for (int f = 0; f < 8; ++f)
      bo[f] = *(const bf16x8*)(wsl + (size_t)(so * 8 + f) * 64 * 8);
    {
      bf16x8 ahi, alo;
      split8(a0c, a1c, ahi, alo);
#pragma unroll
      for (int et = 0; et < 4; ++et) {
        acc[et] = __builtin_amdgcn_mfma_f32_16x16x32_bf16(ahi, bc[et * 2 + 0], acc[et], 0, 0, 0);
        acc[et] = __builtin_amdgcn_mfma_f32_16x16x32_bf16(alo, bc[et * 2 + 0], acc[et], 0, 0, 0);
        acc[et] = __builtin_amdgcn_mfma_f32_16x16x32_bf16(ahi, bc[et * 2 + 1], acc[et], 0, 0, 0);
      }
    }
    if (ls + 2 < 64) {
      const int se = s0 + ls + 2;
      a0c = *(const float4*)(xrow + (ls + 2) * 32);
      a1c = *(const float4*)(xrow + (ls + 2) * 32 + 4);
#pragma unroll
      for (int f = 0; f < 8; ++f)
        bc[f] = *(const bf16x8*)(wsl + (size_t)(se * 8 + f) * 64 * 8);
    }
    {
      bf16x8 ahi, alo;
      split8(a0o, a1o, ahi, alo);
#pragma unroll
      for (int et = 0; et < 4; ++et) {
        acc[et] = __builtin_amdgcn_mfma_f32_16x16x32_bf16(ahi, bo[et * 2 + 0], acc[et], 0, 0, 0);
        acc[et] = __builtin_amdgcn_mfma_f32_16x16x32_bf16(alo, bo[et * 2 + 0], acc[et], 0, 0, 0);
        acc[et] = __builtin_amdgcn_mfma_f32_16x16x32_bf16(ahi, bo[et * 2 + 1], acc[et], 0, 0, 0);
      }
    }
  }
  if (wk == 0) {
#pragma unroll
    for (int et = 0; et < 4; ++et)
#pragma unroll
      for (int r = 0; r < 4; ++r) {
        int t = wt * 16 + 4 * kq + r;
        int e = et * 16 + col;
        logits[t * 64 + ((e + t) & 63)] = acc[et][r];
      }
  }
  __syncthreads();
  if (wk == 1) {
#pragma unroll
    for (int et = 0; et < 4; ++et)
#pragma unroll
      for (int r = 0; r < 4; ++r) {
        int t = wt * 16 + 4 * kq + r;
        int e = et * 16 + col;
        logits[t * 64 + ((e + t) & 63)] += acc[et][r];
      }
  }
  __syncthreads();
  if (tid < 64) {
    const int t = tid, gt = tok0 + t;
    float key[8], sv[8]; int idx[8];
#pragma unroll
    for (int j = 0; j < 8; ++j) { key[j] = -1e30f; sv[j] = 0.f; idx[j] = 0; }
    for (int e = 0; e < NE; ++e) {
      float l = logits[t * 64 + ((e + t) & 63)];
      float s = 1.0f / (1.0f + expf(-l));
      float k = s + bias[e];
      float ck = k, cv = s; int ci = e;
#pragma unroll
      for (int j = 0; j < 8; ++j) {
        bool g = ck > key[j];
        float tk = key[j], tv = sv[j]; int ti = idx[j];
        key[j] = g ? ck : tk; sv[j] = g ? cv : tv; idx[j] = g ? ci : ti;
        ck = g ? tk : ck;     cv = g ? tv : cv;    ci = g ? ti : ci;
      }
    }
    float sum = 1e-20f;
#pragma unroll
    for (int j = 0; j < 8; ++j) sum += sv[j];
    float inv = 1.0f / sum;
#pragma unroll
    for (int j = 0; j < 8; ++j) {
      out_scores[gt * 8 + j] = sv[j] * inv;
      out_idx[gt * 8 + j]    = (float)idx[j];
      atomicAdd(&counts[idx[j]], 1.0f);
    }
  }
}

// ---------- R5 proven last-resort fallback (fp32 scalar-w) ----------
constexpr int KSTEP = 32;
constexpr int FNSTEP = DIM / KSTEP;
constexpr int ROWF4 = 9;
constexpr int BUF4  = 64 * ROWF4;

__global__ __launch_bounds__(512, 2)
void router_fallback(const float* __restrict__ x, const float* __restrict__ w,
                     const float* __restrict__ bias,
                     float* __restrict__ out_scores, float* __restrict__ out_idx,
                     float* __restrict__ counts) {
  __shared__ float4 lds4[2 * BUF4];
  float* ldsf = (float*)lds4;
  const int tid  = threadIdx.x;
  const int lane = tid & 63;
  const int eg   = __builtin_amdgcn_readfirstlane(tid >> 6);
  const int tok0 = blockIdx.x * 64;
  const int r0 = tid >> 3, j0 = tid & 7;
  const float* gp = &x[(size_t)(tok0 + r0) * DIM + j0 * 4];
  const int l0 = r0 * ROWF4 + j0;
  float acc[8];
#pragma unroll
  for (int e = 0; e < 8; ++e) acc[e] = 0.f;
  lds4[l0] = *(const float4*)gp;
  __syncthreads();
  const float* wbase = w + (size_t)eg * 8 * DIM;
#pragma unroll 1
  for (int c = 0; c < FNSTEP; ++c) {
    float4 pf;
    if (c + 1 < FNSTEP) pf = *(const float4*)(gp + (c + 1) * KSTEP);
    float xr[KSTEP];
    {
      const float4* xrow = lds4 + (c & 1) * BUF4 + lane * ROWF4;
#pragma unroll
      for (int i = 0; i < 8; ++i) {
        float4 q = xrow[i];
        xr[4 * i + 0] = q.x; xr[4 * i + 1] = q.y;
        xr[4 * i + 2] = q.z; xr[4 * i + 3] = q.w;
      }
    }
#pragma unroll
    for (int e = 0; e < 8; ++e) {
      const float* wr = wbase + e * DIM + c * KSTEP;
#pragma unroll
      for (int k = 0; k < KSTEP; ++k) acc[e] = fmaf(xr[k], wr[k], acc[e]);
    }
    if (c + 1 < FNSTEP) lds4[((c + 1) & 1) * BUF4 + l0] = pf;
    __syncthreads();
  }
#pragma unroll
  for (int j = 0; j < 8; ++j) {
    int e = eg * 8 + j;
    ldsf[lane * 64 + ((e + lane) & 63)] = acc[j];
  }
  __syncthreads();
  if (tid < 64) {
    const int t = tid, gt = tok0 + t;
    float key[8], sv[8]; int idx[8];
#pragma unroll
    for (int j = 0; j < 8; ++j) { key[j] = -1e30f; sv[j] = 0.f; idx[j] = 0; }
    for (int e = 0; e < NE; ++e) {
      float l = ldsf[t * 64 + ((e + t) & 63)];
      float s = 1.0f / (1.0f + expf(-l));
      float k = s + bias[e];
      float ck = k, cv = s; int ci = e;
#pragma unroll
      for (int j = 0; j < 8; ++j) {
        bool g = ck > key[j];
        float tk = key[j], tv = sv[j]; int ti = idx[j];
        key[j] = g ? ck : tk; sv[j] = g ? cv : tv; idx[j] = g ? ci : ti;
        ck = g ? tk : ck;     cv = g ? tv : cv;    ci = g ? ti : ci;
      }
    }
    float sum = 1e-20f;
#pragma unroll
    for (int j = 0; j < 8; ++j) sum += sv[j];
    float inv = 1.0f / sum;
#pragma unroll
    for (int j = 0; j < 8; ++j) {
      out_scores[gt * 8 + j] = sv[j] * inv;
      out_idx[gt * 8 + j]    = (float)idx[j];
      atomicAdd(&counts[idx[j]], 1.0f);
    }
  }
}

extern "C" void kernel_launch(void* const* d_in, const int* in_sizes, int n_in,
                              void* d_out, int out_size, void* d_ws, size_t ws_size,
                              hipStream_t stream) {
  const float* x    = (const float*)d_in[0];
  const float* w    = (const float*)d_in[1];
  const float* bias = (const float*)d_in[2];

  const int ntok = in_sizes[0] / DIM;              // 16384
  float* out        = (float*)d_out;
  float* out_scores = out;
  float* out_idx    = out + ntok * 8;
  float* counts     = out + 2 * ntok * 8;

  hipMemsetAsync(counts, 0, NE * sizeof(float), stream);

  const int    nblk      = ntok / 32;              // 512
  const size_t wsh_bytes = (size_t)nblk * NE * sizeof(float);  // 128 KB
  const size_t need = WSB_BYTES + wsh_bytes;

  if (ws_size >= need && (ntok % 32) == 0) {
    ushort* wsB = (ushort*)d_ws;
    float*  wsH = (float*)((char*)d_ws + WSB_BYTES);
    hipLaunchKernelGGL(pack_w, dim3(256), dim3(256), 0, stream, w, wsB);
    hipLaunchKernelGGL(router_fused, dim3(nblk), dim3(256), 0, stream,
                       x, (const char*)wsB, bias, out_scores, out_idx, wsH);
    hipLaunchKernelGGL(router_k5, dim3(NE), dim3(64), 0, stream,
                       wsH, counts, nblk);
  } else if (ws_size >= WSB_BYTES) {
    ushort* wsB = (ushort*)d_ws;
    hipLaunchKernelGGL(pack_w, dim3(256), dim3(256), 0, stream, w, wsB);
    hipLaunchKernelGGL(router_mfma, dim3(ntok / 64), dim3(512), 0, stream,
                       x, wsB, bias, out_scores, out_idx, counts);
  } else {
    hipLaunchKernelGGL(router_fallback, dim3(ntok / 64), dim3(512), 0, stream,
                       x, w, bias, out_scores, out_idx, counts);
  }
}